// Round 1
// baseline (642.977 us; speedup 1.0000x reference)
//
#include <hip/hip_runtime.h>
#include <hip/hip_bf16.h>

#define CDIM 128
#define LMAXC 512
#define QBLK 64
#define KVBLK 64

typedef __attribute__((ext_vector_type(8))) short bf16x8;
typedef __attribute__((ext_vector_type(4))) float f32x4;

__device__ inline short f2bf(float f) {
    union { float f; unsigned u; } v; v.f = f;
    unsigned r = v.u + 0x7FFFu + ((v.u >> 16) & 1u);
    return (short)(r >> 16);
}

__device__ inline bf16x8 cvt8v(float4 a, float4 b) {
    bf16x8 o;
    o[0] = f2bf(a.x); o[1] = f2bf(a.y); o[2] = f2bf(a.z); o[3] = f2bf(a.w);
    o[4] = f2bf(b.x); o[5] = f2bf(b.y); o[6] = f2bf(b.z); o[7] = f2bf(b.w);
    return o;
}

// ---------------------------------------------------------------------------
// Projection: out[i][j] = sum_k X[i][k] * W[j][k] + b[j], stored bf16.
// grid = (N/128, 2): y==0 -> Q from Qf; y==1 -> K and V from Kf (shared A frags).
// No LDS: A/B fragments read directly from global (W stays L2-resident).
// ---------------------------------------------------------------------------
__global__ __launch_bounds__(256) void proj_kernel(
    const float* __restrict__ Qf, const float* __restrict__ Kf,
    const float* __restrict__ Wq, const float* __restrict__ bq,
    const float* __restrict__ Wk, const float* __restrict__ bk,
    const float* __restrict__ Wv, const float* __restrict__ bv,
    short* __restrict__ Qp, short* __restrict__ Kp, short* __restrict__ Vp)
{
    const int tid   = threadIdx.x;
    const int lane  = tid & 63;
    const int wv    = tid >> 6;      // wave 0..3, owns 32 rows
    const int lrow  = lane & 15;
    const int lhalf = lane >> 4;     // 0..3
    const int row0  = blockIdx.x * 128;
    const bool isQ  = (blockIdx.y == 0);
    const float* X  = isQ ? Qf : Kf;

    // A fragments: row = row0 + wv*32 + rf*16 + lrow ; k = ks*32 + lhalf*8 + e
    bf16x8 afr[2][4];
#pragma unroll
    for (int rf = 0; rf < 2; ++rf) {
        const float* xr = X + (size_t)(row0 + wv * 32 + rf * 16 + lrow) * CDIM;
#pragma unroll
        for (int ks = 0; ks < 4; ++ks) {
            const float4* s = reinterpret_cast<const float4*>(xr + ks * 32 + lhalf * 8);
            afr[rf][ks] = cvt8v(s[0], s[1]);
        }
    }

    const int npass = isQ ? 1 : 2;
    for (int ps = 0; ps < npass; ++ps) {
        const float* W    = isQ ? Wq : (ps == 0 ? Wk : Wv);
        const float* bias = isQ ? bq : (ps == 0 ? bk : bv);
        short* outp       = isQ ? Qp : (ps == 0 ? Kp : Vp);

#pragma unroll
        for (int cf = 0; cf < 8; ++cf) {
            f32x4 acc0 = {0.f, 0.f, 0.f, 0.f};
            f32x4 acc1 = {0.f, 0.f, 0.f, 0.f};
            const float* wr = W + (size_t)(cf * 16 + lrow) * CDIM;
#pragma unroll
            for (int ks = 0; ks < 4; ++ks) {
                const float4* s = reinterpret_cast<const float4*>(wr + ks * 32 + lhalf * 8);
                bf16x8 bfr = cvt8v(s[0], s[1]);
                acc0 = __builtin_amdgcn_mfma_f32_16x16x32_bf16(afr[0][ks], bfr, acc0, 0, 0, 0);
                acc1 = __builtin_amdgcn_mfma_f32_16x16x32_bf16(afr[1][ks], bfr, acc1, 0, 0, 0);
            }
            float bcol = bias[cf * 16 + lrow];
            const int col = cf * 16 + lrow;
#pragma unroll
            for (int r = 0; r < 4; ++r) {
                int row_a = row0 + wv * 32 + lhalf * 4 + r;       // rf = 0
                int row_b = row_a + 16;                           // rf = 1
                outp[(size_t)row_a * CDIM + col] = f2bf(acc0[r] + bcol);
                outp[(size_t)row_b * CDIM + col] = f2bf(acc1[r] + bcol);
            }
        }
    }
}

// ---------------------------------------------------------------------------
// Flash attention over one (segment, q-tile). 4 waves, each owns 16 q rows.
// LDS: K tile [64][128] bf16 (XOR-swizzled), Vt tile [128][64] bf16 (swizzled),
//      P tiles per wave [16][64] bf16 (swizzled).
// ---------------------------------------------------------------------------
__global__ __launch_bounds__(256) void attn_kernel(
    const short* __restrict__ Qp, const short* __restrict__ Kp,
    const short* __restrict__ Vp, const int* __restrict__ offset,
    float* __restrict__ out)
{
    __shared__ __align__(16) char smem[16384 + 16384 + 8192];
    char* lds_k  = smem;            // 64 rows x 256B
    char* lds_vt = smem + 16384;    // 128 rows x 128B
    char* lds_p  = smem + 32768;    // 4 waves x (16 rows x 128B)

    const int seg   = blockIdx.y;
    const int start = (seg == 0) ? 0 : offset[seg - 1];
    int len = offset[seg] - start;
    if (len > LMAXC) len = LMAXC;
    const int q0 = blockIdx.x * QBLK;
    if (q0 >= len) return;

    const int tid   = threadIdx.x;
    const int lane  = tid & 63;
    const int wv    = tid >> 6;
    const int lrow  = lane & 15;
    const int lhalf = lane >> 4;

    const float SCALE = 0.08838834764831845f;   // 1/sqrt(128)
    const float L2E   = 1.4426950408889634f;

    // Q fragments (held in registers for the whole block)
    bf16x8 aq[4];
    {
        int qr = q0 + wv * 16 + lrow;
        if (qr > len - 1) qr = len - 1;
        const short* qrow = Qp + (size_t)(start + qr) * CDIM;
#pragma unroll
        for (int ks = 0; ks < 4; ++ks)
            aq[ks] = *reinterpret_cast<const bf16x8*>(qrow + ks * 32 + lhalf * 8);
    }

    float m_r[4], l_r[4];
    f32x4 acc_o[8];
#pragma unroll
    for (int r = 0; r < 4; ++r) { m_r[r] = -1e30f; l_r[r] = 0.f; }
#pragma unroll
    for (int df = 0; df < 8; ++df) acc_o[df] = (f32x4){0.f, 0.f, 0.f, 0.f};

    const int wbase = wv * (16 * KVBLK * 2);

    for (int kv0 = 0; kv0 < len; kv0 += KVBLK) {
        // ---- stage K tile and transposed V tile ----
#pragma unroll
        for (int p = 0; p < 4; ++p) {
            int c  = p * 256 + tid;          // 1024 chunks of 8 bf16
            int r  = c >> 4;                 // key row 0..63
            int c0 = (c & 15) * 8;           // d
            int grow = kv0 + r;
            if (grow > len - 1) grow = len - 1;
            const size_t gbase = (size_t)(start + grow) * CDIM + c0;
            bf16x8 kvv = *reinterpret_cast<const bf16x8*>(Kp + gbase);
            int kb = (r * 256 + c0 * 2) ^ ((r & 7) << 4);
            *reinterpret_cast<bf16x8*>(lds_k + kb) = kvv;
            bf16x8 vvv = *reinterpret_cast<const bf16x8*>(Vp + gbase);
#pragma unroll
            for (int e = 0; e < 8; ++e) {
                int d = c0 + e;
                int vb = (d * (KVBLK * 2) + r * 2) ^ ((d & 7) << 4);
                *reinterpret_cast<short*>(lds_vt + vb) = vvv[e];
            }
        }
        __syncthreads();

        // ---- S = Q K^T (per wave: 16 q x 64 keys) ----
        f32x4 s[4];
#pragma unroll
        for (int kf = 0; kf < 4; ++kf) {
            s[kf] = (f32x4){0.f, 0.f, 0.f, 0.f};
            int key = kf * 16 + lrow;
#pragma unroll
            for (int ks = 0; ks < 4; ++ks) {
                int kb = (key * 256 + (ks * 32 + lhalf * 8) * 2) ^ ((key & 7) << 4);
                bf16x8 bk_ = *reinterpret_cast<const bf16x8*>(lds_k + kb);
                s[kf] = __builtin_amdgcn_mfma_f32_16x16x32_bf16(aq[ks], bk_, s[kf], 0, 0, 0);
            }
        }

        // ---- online softmax (row = lhalf*4 + r) ----
        float sb[4][4];
        float mnew[4] = {-1e30f, -1e30f, -1e30f, -1e30f};
#pragma unroll
        for (int kf = 0; kf < 4; ++kf) {
            bool masked = (kv0 + kf * 16 + lrow) >= len;
#pragma unroll
            for (int r = 0; r < 4; ++r) {
                float v = masked ? -1e30f : s[kf][r] * SCALE;
                sb[kf][r] = v;
                mnew[r] = fmaxf(mnew[r], v);
            }
        }
#pragma unroll
        for (int off = 1; off < 16; off <<= 1)
#pragma unroll
            for (int r = 0; r < 4; ++r)
                mnew[r] = fmaxf(mnew[r], __shfl_xor(mnew[r], off));

        float alpha[4];
#pragma unroll
        for (int r = 0; r < 4; ++r) {
            float mn = fmaxf(m_r[r], mnew[r]);
            alpha[r] = exp2f((m_r[r] - mn) * L2E);
            m_r[r] = mn;
        }
        float rs[4] = {0.f, 0.f, 0.f, 0.f};
#pragma unroll
        for (int kf = 0; kf < 4; ++kf)
#pragma unroll
            for (int r = 0; r < 4; ++r) {
                float pv = exp2f((sb[kf][r] - m_r[r]) * L2E);
                sb[kf][r] = pv;
                rs[r] += pv;
            }
#pragma unroll
        for (int off = 1; off < 16; off <<= 1)
#pragma unroll
            for (int r = 0; r < 4; ++r)
                rs[r] += __shfl_xor(rs[r], off);
#pragma unroll
        for (int r = 0; r < 4; ++r) l_r[r] = l_r[r] * alpha[r] + rs[r];
#pragma unroll
        for (int df = 0; df < 8; ++df)
#pragma unroll
            for (int r = 0; r < 4; ++r) acc_o[df][r] *= alpha[r];

        // ---- P -> LDS (re-layout for A operand) ----
#pragma unroll
        for (int kf = 0; kf < 4; ++kf)
#pragma unroll
            for (int r = 0; r < 4; ++r) {
                int q = lhalf * 4 + r;
                int colb = (kf * 16 + lrow) * 2;
                int pb = wbase + ((q * (KVBLK * 2) + colb) ^ ((q & 7) << 4));
                *reinterpret_cast<short*>(lds_p + pb) = f2bf(sb[kf][r]);
            }
        __syncthreads();

        // ---- O += P V ----
#pragma unroll
        for (int ks2 = 0; ks2 < 2; ++ks2) {
            int k0 = ks2 * 32 + lhalf * 8;
            int pb = wbase + ((lrow * (KVBLK * 2) + k0 * 2) ^ ((lrow & 7) << 4));
            bf16x8 ap = *reinterpret_cast<const bf16x8*>(lds_p + pb);
#pragma unroll
            for (int df = 0; df < 8; ++df) {
                int d = df * 16 + lrow;
                int vb = (d * (KVBLK * 2) + k0 * 2) ^ ((d & 7) << 4);
                bf16x8 bv_ = *reinterpret_cast<const bf16x8*>(lds_vt + vb);
                acc_o[df] = __builtin_amdgcn_mfma_f32_16x16x32_bf16(ap, bv_, acc_o[df], 0, 0, 0);
            }
        }
        __syncthreads();
    }

    // ---- epilogue ----
#pragma unroll
    for (int df = 0; df < 8; ++df)
#pragma unroll
        for (int r = 0; r < 4; ++r) {
            int q = wv * 16 + lhalf * 4 + r;
            if (q0 + q < len) {
                float v = acc_o[df][r] / l_r[r];
                out[(size_t)(start + q0 + q) * CDIM + df * 16 + lrow] = v;
            }
        }
}

extern "C" void kernel_launch(void* const* d_in, const int* in_sizes, int n_in,
                              void* d_out, int out_size, void* d_ws, size_t ws_size,
                              hipStream_t stream) {
    const float* Qf = (const float*)d_in[0];
    const float* Kf = (const float*)d_in[1];
    const float* Wq = (const float*)d_in[2];
    const float* bq = (const float*)d_in[3];
    const float* Wk = (const float*)d_in[4];
    const float* bk = (const float*)d_in[5];
    const float* bv_ = (const float*)d_in[7];
    const float* Wv = (const float*)d_in[6];
    const int* offset = (const int*)d_in[8];

    const int N = in_sizes[0] / CDIM;     // 262144
    const int B = in_sizes[8];            // 512

    short* Qp = (short*)d_ws;
    short* Kp = Qp + (size_t)N * CDIM;
    short* Vp = Kp + (size_t)N * CDIM;
    float* out = (float*)d_out;

    dim3 pgrid(N / 128, 2);
    proj_kernel<<<pgrid, 256, 0, stream>>>(Qf, Kf, Wq, bq, Wk, bk, Wv, bv_,
                                           Qp, Kp, Vp);

    dim3 agrid(LMAXC / QBLK, B);
    attn_kernel<<<agrid, 256, 0, stream>>>(Qp, Kp, Vp, offset, out);
}

// Round 2
// 407.160 us; speedup vs baseline: 1.5792x; 1.5792x over previous
//
#include <hip/hip_runtime.h>
#include <hip/hip_bf16.h>

#define CDIM 128
#define LMAXC 512
#define QBLK 64
#define KVBLK 64

typedef __attribute__((ext_vector_type(8))) short bf16x8;
typedef __attribute__((ext_vector_type(4))) short bf16x4;
typedef __attribute__((ext_vector_type(4))) float f32x4;

__device__ inline short f2bf(float f) {
    union { float f; unsigned u; } v; v.f = f;
    unsigned r = v.u + 0x7FFFu + ((v.u >> 16) & 1u);
    return (short)(r >> 16);
}

__device__ inline bf16x8 cvt8v(float4 a, float4 b) {
    bf16x8 o;
    o[0] = f2bf(a.x); o[1] = f2bf(a.y); o[2] = f2bf(a.z); o[3] = f2bf(a.w);
    o[4] = f2bf(b.x); o[5] = f2bf(b.y); o[6] = f2bf(b.z); o[7] = f2bf(b.w);
    return o;
}

// ---------------------------------------------------------------------------
// One-shot W conversion: Wq|Wk|Wv fp32 -> bf16 (3 x 128 x 128).
// ---------------------------------------------------------------------------
__global__ void wcvt_kernel(const float* __restrict__ Wq,
                            const float* __restrict__ Wk,
                            const float* __restrict__ Wv,
                            short* __restrict__ Wbf)
{
    int t = blockIdx.x * 256 + threadIdx.x;   // 6144 threads x 8 elems
    int m = t / 2048;                          // matrix 0..2
    int e = (t % 2048) * 8;
    const float* W = (m == 0) ? Wq : (m == 1) ? Wk : Wv;
    const float4* s = reinterpret_cast<const float4*>(W + e);
    *reinterpret_cast<bf16x8*>(Wbf + m * 16384 + e) = cvt8v(s[0], s[1]);
}

// ---------------------------------------------------------------------------
// Projection. grid = (N/128, 2): y==0 -> Q; y==1 -> K then V (shared A frags).
// Q,K written row-major bf16. V written TRANSPOSED (Vt[C][N]) via LDS tile
// so the attention kernel can stage it coalesced.
// ---------------------------------------------------------------------------
__global__ __launch_bounds__(256) void proj_kernel(
    const float* __restrict__ Qf, const float* __restrict__ Kf,
    const short* __restrict__ Wbf,
    const float* __restrict__ bq, const float* __restrict__ bk,
    const float* __restrict__ bv,
    short* __restrict__ Qp, short* __restrict__ Kp, short* __restrict__ Vt,
    int N)
{
    __shared__ __align__(16) char vt_lds[32768];   // 128 cols x 128 rows bf16

    const int tid   = threadIdx.x;
    const int lane  = tid & 63;
    const int wv    = tid >> 6;
    const int lrow  = lane & 15;
    const int lhalf = lane >> 4;
    const int row0  = blockIdx.x * 128;
    const bool isQ  = (blockIdx.y == 0);
    const float* X  = isQ ? Qf : Kf;

    // A fragments: row = row0 + wv*32 + rf*16 + lrow ; k = ks*32 + lhalf*8 + e
    bf16x8 afr[2][4];
#pragma unroll
    for (int rf = 0; rf < 2; ++rf) {
        const float* xr = X + (size_t)(row0 + wv * 32 + rf * 16 + lrow) * CDIM;
#pragma unroll
        for (int ks = 0; ks < 4; ++ks) {
            const float4* s = reinterpret_cast<const float4*>(xr + ks * 32 + lhalf * 8);
            afr[rf][ks] = cvt8v(s[0], s[1]);
        }
    }

    const int npass = isQ ? 1 : 2;
    for (int ps = 0; ps < npass; ++ps) {
        const int midx    = isQ ? 0 : (ps == 0 ? 1 : 2);
        const short* W    = Wbf + midx * 16384;
        const float* bias = isQ ? bq : (ps == 0 ? bk : bv);
        const bool toVt   = (!isQ) && (ps == 1);
        short* outp       = isQ ? Qp : Kp;

#pragma unroll
        for (int cf = 0; cf < 8; ++cf) {
            f32x4 acc0 = {0.f, 0.f, 0.f, 0.f};
            f32x4 acc1 = {0.f, 0.f, 0.f, 0.f};
            const short* wr = W + (cf * 16 + lrow) * CDIM;
#pragma unroll
            for (int ks = 0; ks < 4; ++ks) {
                bf16x8 bfr = *reinterpret_cast<const bf16x8*>(wr + ks * 32 + lhalf * 8);
                acc0 = __builtin_amdgcn_mfma_f32_16x16x32_bf16(afr[0][ks], bfr, acc0, 0, 0, 0);
                acc1 = __builtin_amdgcn_mfma_f32_16x16x32_bf16(afr[1][ks], bfr, acc1, 0, 0, 0);
            }
            const int col = cf * 16 + lrow;
            float bcol = bias[col];
            if (!toVt) {
#pragma unroll
                for (int r = 0; r < 4; ++r) {
                    int row_a = row0 + wv * 32 + lhalf * 4 + r;
                    outp[(size_t)row_a * CDIM + col]        = f2bf(acc0[r] + bcol);
                    outp[(size_t)(row_a + 16) * CDIM + col] = f2bf(acc1[r] + bcol);
                }
            } else {
                bf16x4 p0, p1;
#pragma unroll
                for (int r = 0; r < 4; ++r) {
                    p0[r] = f2bf(acc0[r] + bcol);
                    p1[r] = f2bf(acc1[r] + bcol);
                }
                int base = col * 256 + wv * 64 + lhalf * 8;
                int sw   = (col & 7) << 4;
                *reinterpret_cast<bf16x4*>(vt_lds + ((base)      ^ sw)) = p0;
                *reinterpret_cast<bf16x4*>(vt_lds + ((base + 32) ^ sw)) = p1;
            }
        }

        if (toVt) {
            __syncthreads();
#pragma unroll
            for (int it = 0; it < 8; ++it) {
                int c   = it * 256 + tid;
                int col = c >> 4, rc = c & 15;
                int a   = (col * 256 + rc * 16) ^ ((col & 7) << 4);
                bf16x8 v = *reinterpret_cast<const bf16x8*>(vt_lds + a);
                *reinterpret_cast<bf16x8*>(Vt + (size_t)col * N + row0 + rc * 8) = v;
            }
        }
    }
}

// ---------------------------------------------------------------------------
// Flash attention. K staged row-major (swizzled); Vt staged from the
// pre-transposed global Vt[C][N] with coalesced swizzled bf16x8 writes.
// ---------------------------------------------------------------------------
__global__ __launch_bounds__(256) void attn_kernel(
    const short* __restrict__ Qp, const short* __restrict__ Kp,
    const short* __restrict__ VtG, const int* __restrict__ offset,
    float* __restrict__ out, int Ntot)
{
    __shared__ __align__(16) char smem[16384 + 16384 + 8192];
    char* lds_k  = smem;            // 64 keys x 256B
    char* lds_vt = smem + 16384;    // 128 d-rows x 128B
    char* lds_p  = smem + 32768;    // 4 waves x (16 q x 128B)

    const int seg   = blockIdx.y;
    const int start = (seg == 0) ? 0 : offset[seg - 1];
    int len = offset[seg] - start;
    if (len > LMAXC) len = LMAXC;
    const int q0 = blockIdx.x * QBLK;
    if (q0 >= len) return;

    const int tid   = threadIdx.x;
    const int lane  = tid & 63;
    const int wv    = tid >> 6;
    const int lrow  = lane & 15;
    const int lhalf = lane >> 4;

    const float SCALE = 0.08838834764831845f;   // 1/sqrt(128)
    const float L2E   = 1.4426950408889634f;

    bf16x8 aq[4];
    {
        int qr = q0 + wv * 16 + lrow;
        if (qr > len - 1) qr = len - 1;
        const short* qrow = Qp + (size_t)(start + qr) * CDIM;
#pragma unroll
        for (int ks = 0; ks < 4; ++ks)
            aq[ks] = *reinterpret_cast<const bf16x8*>(qrow + ks * 32 + lhalf * 8);
    }

    float m_r[4], l_r[4];
    f32x4 acc_o[8];
#pragma unroll
    for (int r = 0; r < 4; ++r) { m_r[r] = -1e30f; l_r[r] = 0.f; }
#pragma unroll
    for (int df = 0; df < 8; ++df) acc_o[df] = (f32x4){0.f, 0.f, 0.f, 0.f};

    const int wbase = wv * (16 * KVBLK * 2);

    for (int kv0 = 0; kv0 < len; kv0 += KVBLK) {
        // ---- stage K tile (row-major, swizzled) ----
#pragma unroll
        for (int p = 0; p < 4; ++p) {
            int c  = p * 256 + tid;
            int r  = c >> 4;
            int c0 = (c & 15) * 8;
            int grow = kv0 + r;
            if (grow > len - 1) grow = len - 1;
            bf16x8 kvv = *reinterpret_cast<const bf16x8*>(
                Kp + (size_t)(start + grow) * CDIM + c0);
            int kb = (r * 256 + c0 * 2) ^ ((r & 7) << 4);
            *reinterpret_cast<bf16x8*>(lds_k + kb) = kvv;
        }
        // ---- stage Vt tile (d-major rows of 64 keys, swizzled) ----
#pragma unroll
        for (int p = 0; p < 4; ++p) {
            int c    = p * 256 + tid;
            int d    = c >> 3;
            int koff = (c & 7) * 8;
            long gk  = (long)start + kv0 + koff;
            if (gk + 8 > Ntot) gk = Ntot - 8;   // never triggers for valid keys here
            bf16x8 vv = *reinterpret_cast<const bf16x8*>(VtG + (size_t)d * Ntot + gk);
            int vb = (d * (KVBLK * 2) + koff * 2) ^ ((d & 7) << 4);
            *reinterpret_cast<bf16x8*>(lds_vt + vb) = vv;
        }
        __syncthreads();

        // ---- S = Q K^T ----
        f32x4 s[4];
#pragma unroll
        for (int kf = 0; kf < 4; ++kf) {
            s[kf] = (f32x4){0.f, 0.f, 0.f, 0.f};
            int key = kf * 16 + lrow;
#pragma unroll
            for (int ks = 0; ks < 4; ++ks) {
                int kb = (key * 256 + (ks * 32 + lhalf * 8) * 2) ^ ((key & 7) << 4);
                bf16x8 bk_ = *reinterpret_cast<const bf16x8*>(lds_k + kb);
                s[kf] = __builtin_amdgcn_mfma_f32_16x16x32_bf16(aq[ks], bk_, s[kf], 0, 0, 0);
            }
        }

        // ---- online softmax (row = lhalf*4 + r) ----
        float sb[4][4];
        float mnew[4] = {-1e30f, -1e30f, -1e30f, -1e30f};
#pragma unroll
        for (int kf = 0; kf < 4; ++kf) {
            bool masked = (kv0 + kf * 16 + lrow) >= len;
#pragma unroll
            for (int r = 0; r < 4; ++r) {
                float v = masked ? -1e30f : s[kf][r] * SCALE;
                sb[kf][r] = v;
                mnew[r] = fmaxf(mnew[r], v);
            }
        }
#pragma unroll
        for (int off = 1; off < 16; off <<= 1)
#pragma unroll
            for (int r = 0; r < 4; ++r)
                mnew[r] = fmaxf(mnew[r], __shfl_xor(mnew[r], off));

        float alpha[4];
#pragma unroll
        for (int r = 0; r < 4; ++r) {
            float mn = fmaxf(m_r[r], mnew[r]);
            alpha[r] = exp2f((m_r[r] - mn) * L2E);
            m_r[r] = mn;
        }
        float rs[4] = {0.f, 0.f, 0.f, 0.f};
#pragma unroll
        for (int kf = 0; kf < 4; ++kf)
#pragma unroll
            for (int r = 0; r < 4; ++r) {
                float pv = exp2f((sb[kf][r] - m_r[r]) * L2E);
                sb[kf][r] = pv;
                rs[r] += pv;
            }
#pragma unroll
        for (int off = 1; off < 16; off <<= 1)
#pragma unroll
            for (int r = 0; r < 4; ++r)
                rs[r] += __shfl_xor(rs[r], off);
#pragma unroll
        for (int r = 0; r < 4; ++r) l_r[r] = l_r[r] * alpha[r] + rs[r];
#pragma unroll
        for (int df = 0; df < 8; ++df)
#pragma unroll
            for (int r = 0; r < 4; ++r) acc_o[df][r] *= alpha[r];

        // ---- P -> LDS (re-layout for A operand) ----
#pragma unroll
        for (int kf = 0; kf < 4; ++kf)
#pragma unroll
            for (int r = 0; r < 4; ++r) {
                int q = lhalf * 4 + r;
                int colb = (kf * 16 + lrow) * 2;
                int pb = wbase + ((q * (KVBLK * 2) + colb) ^ ((q & 7) << 4));
                *reinterpret_cast<short*>(lds_p + pb) = f2bf(sb[kf][r]);
            }
        __syncthreads();

        // ---- O += P V ----
#pragma unroll
        for (int ks2 = 0; ks2 < 2; ++ks2) {
            int k0 = ks2 * 32 + lhalf * 8;
            int pb = wbase + ((lrow * (KVBLK * 2) + k0 * 2) ^ ((lrow & 7) << 4));
            bf16x8 ap = *reinterpret_cast<const bf16x8*>(lds_p + pb);
#pragma unroll
            for (int df = 0; df < 8; ++df) {
                int d = df * 16 + lrow;
                int vb = (d * (KVBLK * 2) + k0 * 2) ^ ((d & 7) << 4);
                bf16x8 bv_ = *reinterpret_cast<const bf16x8*>(lds_vt + vb);
                acc_o[df] = __builtin_amdgcn_mfma_f32_16x16x32_bf16(ap, bv_, acc_o[df], 0, 0, 0);
            }
        }
        __syncthreads();
    }

    // ---- epilogue ----
#pragma unroll
    for (int df = 0; df < 8; ++df)
#pragma unroll
        for (int r = 0; r < 4; ++r) {
            int q = wv * 16 + lhalf * 4 + r;
            if (q0 + q < len) {
                float v = acc_o[df][r] / l_r[r];
                out[(size_t)(start + q0 + q) * CDIM + df * 16 + lrow] = v;
            }
        }
}

extern "C" void kernel_launch(void* const* d_in, const int* in_sizes, int n_in,
                              void* d_out, int out_size, void* d_ws, size_t ws_size,
                              hipStream_t stream) {
    const float* Qf = (const float*)d_in[0];
    const float* Kf = (const float*)d_in[1];
    const float* Wq = (const float*)d_in[2];
    const float* bq = (const float*)d_in[3];
    const float* Wk = (const float*)d_in[4];
    const float* bk = (const float*)d_in[5];
    const float* Wv = (const float*)d_in[6];
    const float* bv_ = (const float*)d_in[7];
    const int* offset = (const int*)d_in[8];

    const int N = in_sizes[0] / CDIM;     // 262144
    const int B = in_sizes[8];            // 512

    short* Qp = (short*)d_ws;
    short* Kp = Qp + (size_t)N * CDIM;
    short* Vt = Kp + (size_t)N * CDIM;    // [C][N] transposed V
    float* out = (float*)d_out;

    // bf16 weights: ws tail if it fits, else head of d_out (fully overwritten
    // by attn afterwards, stream-ordered).
    size_t base_need = (size_t)3 * N * CDIM * 2;
    short* Wbf = (ws_size >= base_need + 3 * 16384 * 2)
               ? (Vt + (size_t)N * CDIM) : (short*)d_out;

    wcvt_kernel<<<24, 256, 0, stream>>>(Wq, Wk, Wv, Wbf);

    dim3 pgrid(N / 128, 2);
    proj_kernel<<<pgrid, 256, 0, stream>>>(Qf, Kf, Wbf, bq, bk, bv_,
                                           Qp, Kp, Vt, N);

    dim3 agrid(LMAXC / QBLK, B);
    attn_kernel<<<agrid, 256, 0, stream>>>(Qp, Kp, Vt, offset, out, N);
}

// Round 3
// 351.456 us; speedup vs baseline: 1.8295x; 1.1585x over previous
//
#include <hip/hip_runtime.h>
#include <hip/hip_bf16.h>

#define CDIM 128
#define LMAXC 512
#define QBLK 128
#define KVBLK 64

typedef __attribute__((ext_vector_type(8))) short bf16x8;
typedef __attribute__((ext_vector_type(4))) short bf16x4;
typedef __attribute__((ext_vector_type(4))) float f32x4;

// 1/sqrt(128) * log2(e), folded into Wq/bq so softmax is exp2(s) directly
#define QSCALE (0.08838834764831845f * 1.4426950408889634f)

__device__ inline short f2bf(float f) {
    union { float f; unsigned u; } v; v.f = f;
    unsigned r = v.u + 0x7FFFu + ((v.u >> 16) & 1u);
    return (short)(r >> 16);
}

__device__ inline bf16x8 cvt8v(float4 a, float4 b) {
    bf16x8 o;
    o[0] = f2bf(a.x); o[1] = f2bf(a.y); o[2] = f2bf(a.z); o[3] = f2bf(a.w);
    o[4] = f2bf(b.x); o[5] = f2bf(b.y); o[6] = f2bf(b.z); o[7] = f2bf(b.w);
    return o;
}

// ---------------------------------------------------------------------------
// One-shot W conversion (Wq scaled by QSCALE).
// ---------------------------------------------------------------------------
__global__ void wcvt_kernel(const float* __restrict__ Wq,
                            const float* __restrict__ Wk,
                            const float* __restrict__ Wv,
                            short* __restrict__ Wbf)
{
    int t = blockIdx.x * 256 + threadIdx.x;
    int m = t / 2048;
    int e = (t % 2048) * 8;
    const float* W = (m == 0) ? Wq : (m == 1) ? Wk : Wv;
    float sc = (m == 0) ? QSCALE : 1.0f;
    float4 a = *reinterpret_cast<const float4*>(W + e);
    float4 b = *reinterpret_cast<const float4*>(W + e + 4);
    a.x *= sc; a.y *= sc; a.z *= sc; a.w *= sc;
    b.x *= sc; b.y *= sc; b.z *= sc; b.w *= sc;
    *reinterpret_cast<bf16x8*>(Wbf + m * 16384 + e) = cvt8v(a, b);
}

// ---------------------------------------------------------------------------
// Projection. y==0: Q (swapped-operand, row-major 8B stores). y==1: K
// (swapped-operand) then V -> transposed Vt[C][N] via LDS.
// ---------------------------------------------------------------------------
__global__ __launch_bounds__(256) void proj_kernel(
    const float* __restrict__ Qf, const float* __restrict__ Kf,
    const short* __restrict__ Wbf,
    const float* __restrict__ bq, const float* __restrict__ bk,
    const float* __restrict__ bv,
    short* __restrict__ Qp, short* __restrict__ Kp, short* __restrict__ Vt,
    int N)
{
    __shared__ __align__(16) char vt_lds[32768];

    const int tid   = threadIdx.x;
    const int lane  = tid & 63;
    const int wv    = tid >> 6;
    const int lrow  = lane & 15;
    const int lhalf = lane >> 4;
    const int row0  = blockIdx.x * 128;
    const bool isQ  = (blockIdx.y == 0);
    const float* X  = isQ ? Qf : Kf;

    // X fragments: row = row0 + wv*32 + xt*16 + lrow ; k = ks*32 + lhalf*8 + e
    bf16x8 xfr[2][4];
#pragma unroll
    for (int xt = 0; xt < 2; ++xt) {
        const float* xr = X + (size_t)(row0 + wv * 32 + xt * 16 + lrow) * CDIM;
#pragma unroll
        for (int ks = 0; ks < 4; ++ks) {
            const float4* s = reinterpret_cast<const float4*>(xr + ks * 32 + lhalf * 8);
            xfr[xt][ks] = cvt8v(s[0], s[1]);
        }
    }

    // ---- row-major output pass(es): Q (y==0) or K (y==1), swapped operands
    {
        const short* W    = isQ ? Wbf : Wbf + 16384;
        const float* bias = isQ ? bq : bk;
        const float  bsc  = isQ ? QSCALE : 1.0f;
        short* outp       = isQ ? Qp : Kp;

#pragma unroll
        for (int cf = 0; cf < 8; ++cf) {
            const short* wr = W + (cf * 16 + lrow) * CDIM;
            bf16x8 wfr[4];
#pragma unroll
            for (int ks = 0; ks < 4; ++ks)
                wfr[ks] = *reinterpret_cast<const bf16x8*>(wr + ks * 32 + lhalf * 8);
            float4 bv4 = *reinterpret_cast<const float4*>(bias + cf * 16 + lhalf * 4);
#pragma unroll
            for (int xt = 0; xt < 2; ++xt) {
                f32x4 acc = {0.f, 0.f, 0.f, 0.f};
#pragma unroll
                for (int ks = 0; ks < 4; ++ks)
                    acc = __builtin_amdgcn_mfma_f32_16x16x32_bf16(wfr[ks], xfr[xt][ks], acc, 0, 0, 0);
                bf16x4 pk;
                pk[0] = f2bf(acc[0] + bv4.x * bsc);
                pk[1] = f2bf(acc[1] + bv4.y * bsc);
                pk[2] = f2bf(acc[2] + bv4.z * bsc);
                pk[3] = f2bf(acc[3] + bv4.w * bsc);
                *reinterpret_cast<bf16x4*>(
                    outp + (size_t)(row0 + wv * 32 + xt * 16 + lrow) * CDIM
                         + cf * 16 + lhalf * 4) = pk;
            }
        }
    }

    // ---- V pass (y==1 only): original operand order -> Vt[C][N] via LDS
    if (!isQ) {
        const short* W = Wbf + 32768;
#pragma unroll
        for (int cf = 0; cf < 8; ++cf) {
            f32x4 acc0 = {0.f, 0.f, 0.f, 0.f};
            f32x4 acc1 = {0.f, 0.f, 0.f, 0.f};
            const short* wr = W + (cf * 16 + lrow) * CDIM;
#pragma unroll
            for (int ks = 0; ks < 4; ++ks) {
                bf16x8 bfr = *reinterpret_cast<const bf16x8*>(wr + ks * 32 + lhalf * 8);
                acc0 = __builtin_amdgcn_mfma_f32_16x16x32_bf16(xfr[0][ks], bfr, acc0, 0, 0, 0);
                acc1 = __builtin_amdgcn_mfma_f32_16x16x32_bf16(xfr[1][ks], bfr, acc1, 0, 0, 0);
            }
            const int col = cf * 16 + lrow;
            float bcol = bv[col];
            bf16x4 p0, p1;
#pragma unroll
            for (int r = 0; r < 4; ++r) {
                p0[r] = f2bf(acc0[r] + bcol);
                p1[r] = f2bf(acc1[r] + bcol);
            }
            int base = col * 256 + wv * 64 + lhalf * 8;
            int sw   = (col & 7) << 4;
            *reinterpret_cast<bf16x4*>(vt_lds + ((base)      ^ sw)) = p0;
            *reinterpret_cast<bf16x4*>(vt_lds + ((base + 32) ^ sw)) = p1;
        }
        __syncthreads();
#pragma unroll
        for (int it = 0; it < 8; ++it) {
            int c   = it * 256 + tid;
            int col = c >> 4, rc = c & 15;
            int a   = (col * 256 + rc * 16) ^ ((col & 7) << 4);
            bf16x8 v = *reinterpret_cast<const bf16x8*>(vt_lds + a);
            *reinterpret_cast<bf16x8*>(Vt + (size_t)col * N + row0 + rc * 8) = v;
        }
    }
}

// ---------------------------------------------------------------------------
// Flash attention, flat exp2-sum softmax (no max tracking), QBLK=128.
// grid = (B segments, LMAX/QBLK) so same-seg blocks share an XCD.
// ---------------------------------------------------------------------------
__device__ inline int pch(int q) { return ((q + (q >> 3)) & 7) << 4; }

__global__ __launch_bounds__(256) void attn_kernel(
    const short* __restrict__ Qp, const short* __restrict__ Kp,
    const short* __restrict__ VtG, const int* __restrict__ offset,
    float* __restrict__ out, int Ntot)
{
    __shared__ __align__(16) char smem[16384 + 16384 + 16384];
    char* lds_k  = smem;            // 64 keys x 256B (swizzled)
    char* lds_vt = smem + 16384;    // 128 d x 128B (swizzled)
    char* lds_p  = smem + 32768;    // 4 waves x (32 q x 128B) (swizzled)

    const int seg   = blockIdx.x;
    const int start = (seg == 0) ? 0 : offset[seg - 1];
    int len = offset[seg] - start;
    if (len > LMAXC) len = LMAXC;
    const int q0 = blockIdx.y * QBLK;
    if (q0 >= len) return;

    const int tid   = threadIdx.x;
    const int lane  = tid & 63;
    const int wv    = tid >> 6;
    const int lrow  = lane & 15;
    const int lhalf = lane >> 4;

    // Q fragments for 2 q-tiles of 16 rows each (wave owns 32 q rows)
    bf16x8 aq[2][4];
#pragma unroll
    for (int qt = 0; qt < 2; ++qt) {
        int qr = q0 + wv * 32 + qt * 16 + lrow;
        if (qr > len - 1) qr = len - 1;
        const short* qrow = Qp + (size_t)(start + qr) * CDIM;
#pragma unroll
        for (int ks = 0; ks < 4; ++ks)
            aq[qt][ks] = *reinterpret_cast<const bf16x8*>(qrow + ks * 32 + lhalf * 8);
    }

    f32x4 acc_o[2][8];
    float lsum[2][4];
#pragma unroll
    for (int qt = 0; qt < 2; ++qt) {
#pragma unroll
        for (int df = 0; df < 8; ++df) acc_o[qt][df] = (f32x4){0.f, 0.f, 0.f, 0.f};
#pragma unroll
        for (int r = 0; r < 4; ++r) lsum[qt][r] = 0.f;
    }

    const int wbase = wv * 4096;

    for (int kv0 = 0; kv0 < len; kv0 += KVBLK) {
        // ---- stage K tile ----
#pragma unroll
        for (int p = 0; p < 4; ++p) {
            int c  = p * 256 + tid;
            int r  = c >> 4;
            int c0 = (c & 15) * 8;
            int grow = kv0 + r;
            if (grow > len - 1) grow = len - 1;
            bf16x8 kvv = *reinterpret_cast<const bf16x8*>(
                Kp + (size_t)(start + grow) * CDIM + c0);
            int kb = (r * 256 + c0 * 2) ^ ((r & 7) << 4);
            *reinterpret_cast<bf16x8*>(lds_k + kb) = kvv;
        }
        // ---- stage Vt tile ----
#pragma unroll
        for (int p = 0; p < 4; ++p) {
            int c    = p * 256 + tid;
            int d    = c >> 3;
            int koff = (c & 7) * 8;
            long gk  = (long)start + kv0 + koff;
            if (gk + 8 > Ntot) gk = Ntot - 8;
            bf16x8 vv = *reinterpret_cast<const bf16x8*>(VtG + (size_t)d * Ntot + gk);
            int vb = (d * (KVBLK * 2) + koff * 2) ^ ((d & 7) << 4);
            *reinterpret_cast<bf16x8*>(lds_vt + vb) = vv;
        }
        __syncthreads();

        const bool tail = (kv0 + KVBLK > len);

        // ---- S = Q K^T for both q-tiles (K frags read once) ----
        f32x4 s0[4], s1[4];
#pragma unroll
        for (int kf = 0; kf < 4; ++kf) {
            s0[kf] = (f32x4){0.f, 0.f, 0.f, 0.f};
            s1[kf] = (f32x4){0.f, 0.f, 0.f, 0.f};
            int key = kf * 16 + lrow;
#pragma unroll
            for (int ks = 0; ks < 4; ++ks) {
                int kb = (key * 256 + (ks * 32 + lhalf * 8) * 2) ^ ((key & 7) << 4);
                bf16x8 kfr = *reinterpret_cast<const bf16x8*>(lds_k + kb);
                s0[kf] = __builtin_amdgcn_mfma_f32_16x16x32_bf16(aq[0][ks], kfr, s0[kf], 0, 0, 0);
                s1[kf] = __builtin_amdgcn_mfma_f32_16x16x32_bf16(aq[1][ks], kfr, s1[kf], 0, 0, 0);
            }
        }
        if (tail) {
#pragma unroll
            for (int kf = 0; kf < 4; ++kf) {
                bool mk = (kv0 + kf * 16 + lrow) >= len;
                if (mk) {
                    s0[kf] = (f32x4){-1e30f, -1e30f, -1e30f, -1e30f};
                    s1[kf] = (f32x4){-1e30f, -1e30f, -1e30f, -1e30f};
                }
            }
        }

        // ---- flat softmax: p = exp2(s); accumulate lsum; write P ----
#pragma unroll
        for (int kf = 0; kf < 4; ++kf) {
            int colb = ((kf * 16 + lrow) * 2);
#pragma unroll
            for (int r = 0; r < 4; ++r) {
                int qa = lhalf * 4 + r;
                float pa = exp2f(s0[kf][r]);
                lsum[0][r] += pa;
                *reinterpret_cast<short*>(lds_p + wbase + qa * 128 + (colb ^ pch(qa)))
                    = f2bf(pa);
                int qb = 16 + qa;
                float pb = exp2f(s1[kf][r]);
                lsum[1][r] += pb;
                *reinterpret_cast<short*>(lds_p + wbase + qb * 128 + (colb ^ pch(qb)))
                    = f2bf(pb);
            }
        }
        // per-wave P region: no cross-wave barrier needed

        // ---- O += P V (V frags read once for both q-tiles) ----
#pragma unroll
        for (int ks2 = 0; ks2 < 2; ++ks2) {
            int k0 = ks2 * 32 + lhalf * 8;
            bf16x8 ap0 = *reinterpret_cast<const bf16x8*>(
                lds_p + wbase + lrow * 128 + ((k0 * 2) ^ pch(lrow)));
            bf16x8 ap1 = *reinterpret_cast<const bf16x8*>(
                lds_p + wbase + (16 + lrow) * 128 + ((k0 * 2) ^ pch(16 + lrow)));
#pragma unroll
            for (int df = 0; df < 8; ++df) {
                int d = df * 16 + lrow;
                int vb = (d * (KVBLK * 2) + k0 * 2) ^ ((d & 7) << 4);
                bf16x8 bvf = *reinterpret_cast<const bf16x8*>(lds_vt + vb);
                acc_o[0][df] = __builtin_amdgcn_mfma_f32_16x16x32_bf16(ap0, bvf, acc_o[0][df], 0, 0, 0);
                acc_o[1][df] = __builtin_amdgcn_mfma_f32_16x16x32_bf16(ap1, bvf, acc_o[1][df], 0, 0, 0);
            }
        }
        __syncthreads();
    }

    // ---- epilogue: one l-reduction, then scaled stores ----
    float rinv[2][4];
#pragma unroll
    for (int qt = 0; qt < 2; ++qt)
#pragma unroll
        for (int r = 0; r < 4; ++r) {
            float l = lsum[qt][r];
#pragma unroll
            for (int off = 1; off < 16; off <<= 1)
                l += __shfl_xor(l, off);
            rinv[qt][r] = 1.0f / l;
        }

#pragma unroll
    for (int qt = 0; qt < 2; ++qt)
#pragma unroll
        for (int df = 0; df < 8; ++df)
#pragma unroll
            for (int r = 0; r < 4; ++r) {
                int qg = q0 + wv * 32 + qt * 16 + lhalf * 4 + r;
                if (qg < len)
                    out[(size_t)(start + qg) * CDIM + df * 16 + lrow]
                        = acc_o[qt][df][r] * rinv[qt][r];
            }
}

extern "C" void kernel_launch(void* const* d_in, const int* in_sizes, int n_in,
                              void* d_out, int out_size, void* d_ws, size_t ws_size,
                              hipStream_t stream) {
    const float* Qf = (const float*)d_in[0];
    const float* Kf = (const float*)d_in[1];
    const float* Wq = (const float*)d_in[2];
    const float* bq = (const float*)d_in[3];
    const float* Wk = (const float*)d_in[4];
    const float* bk = (const float*)d_in[5];
    const float* Wv = (const float*)d_in[6];
    const float* bv_ = (const float*)d_in[7];
    const int* offset = (const int*)d_in[8];

    const int N = in_sizes[0] / CDIM;     // 262144
    const int B = in_sizes[8];            // 512

    short* Qp = (short*)d_ws;
    short* Kp = Qp + (size_t)N * CDIM;
    short* Vt = Kp + (size_t)N * CDIM;    // [C][N]
    float* out = (float*)d_out;

    size_t base_need = (size_t)3 * N * CDIM * 2;
    short* Wbf = (ws_size >= base_need + 3 * 16384 * 2)
               ? (Vt + (size_t)N * CDIM) : (short*)d_out;

    wcvt_kernel<<<24, 256, 0, stream>>>(Wq, Wk, Wv, Wbf);

    dim3 pgrid(N / 128, 2);
    proj_kernel<<<pgrid, 256, 0, stream>>>(Qf, Kf, Wbf, bq, bk, bv_,
                                           Qp, Kp, Vt, N);

    dim3 agrid(B, LMAXC / QBLK);
    attn_kernel<<<agrid, 256, 0, stream>>>(Qp, Kp, Vt, offset, out, N);
}

// Round 4
// 279.191 us; speedup vs baseline: 2.3030x; 1.2588x over previous
//
#include <hip/hip_runtime.h>
#include <hip/hip_bf16.h>

#define CDIM 128
#define LMAXC 512
#define QBLK 128
#define KVBLK 64

// 1/sqrt(128) * log2(e), folded into Wq/bq so softmax is exp2(s) directly
#define QSCALE (0.08838834764831845f * 1.4426950408889634f)

typedef __attribute__((ext_vector_type(8))) short bf16x8;
typedef __attribute__((ext_vector_type(4))) short bf16x4;
typedef __attribute__((ext_vector_type(4))) float f32x4;

__device__ inline unsigned pk2(float lo, float hi) {
    unsigned r;
    asm("v_cvt_pk_bf16_f32 %0, %1, %2" : "=v"(r) : "v"(lo), "v"(hi));
    return r;
}

__device__ inline bf16x8 cvt8v(float4 a, float4 b) {
    union { bf16x8 v; unsigned u[4]; } t;
    t.u[0] = pk2(a.x, a.y); t.u[1] = pk2(a.z, a.w);
    t.u[2] = pk2(b.x, b.y); t.u[3] = pk2(b.z, b.w);
    return t.v;
}

__device__ inline void gload16(const void* g, void* l) {
    __builtin_amdgcn_global_load_lds(
        (const __attribute__((address_space(1))) unsigned*)g,
        (__attribute__((address_space(3))) unsigned*)l, 16, 0, 0);
}

__device__ inline void blk_barrier() {
    __builtin_amdgcn_sched_barrier(0);
    __builtin_amdgcn_s_barrier();
    __builtin_amdgcn_sched_barrier(0);
}

__device__ inline int pch(int q) { return ((q + (q >> 3)) & 7) << 4; }

// ---------------------------------------------------------------------------
// One-shot W conversion (Wq scaled by QSCALE).
// ---------------------------------------------------------------------------
__global__ void wcvt_kernel(const float* __restrict__ Wq,
                            const float* __restrict__ Wk,
                            const float* __restrict__ Wv,
                            short* __restrict__ Wbf)
{
    int t = blockIdx.x * 256 + threadIdx.x;
    int m = t / 2048;
    int e = (t % 2048) * 8;
    const float* W = (m == 0) ? Wq : (m == 1) ? Wk : Wv;
    float sc = (m == 0) ? QSCALE : 1.0f;
    float4 a = *reinterpret_cast<const float4*>(W + e);
    float4 b = *reinterpret_cast<const float4*>(W + e + 4);
    a.x *= sc; a.y *= sc; a.z *= sc; a.w *= sc;
    b.x *= sc; b.y *= sc; b.z *= sc; b.w *= sc;
    *reinterpret_cast<bf16x8*>(Wbf + m * 16384 + e) = cvt8v(a, b);
}

// ---------------------------------------------------------------------------
// Projection. y==0: Q (swapped-operand, 8B stores). y==1: K then V->Vt[C][N].
// ---------------------------------------------------------------------------
__global__ __launch_bounds__(256) void proj_kernel(
    const float* __restrict__ Qf, const float* __restrict__ Kf,
    const short* __restrict__ Wbf,
    const float* __restrict__ bq, const float* __restrict__ bk,
    const float* __restrict__ bv,
    short* __restrict__ Qp, short* __restrict__ Kp, short* __restrict__ Vt,
    int N)
{
    __shared__ __align__(16) char vt_lds[32768];

    const int tid   = threadIdx.x;
    const int lane  = tid & 63;
    const int wv    = tid >> 6;
    const int lrow  = lane & 15;
    const int lhalf = lane >> 4;
    const int row0  = blockIdx.x * 128;
    const bool isQ  = (blockIdx.y == 0);
    const float* X  = isQ ? Qf : Kf;

    bf16x8 xfr[2][4];
#pragma unroll
    for (int xt = 0; xt < 2; ++xt) {
        const float* xr = X + (size_t)(row0 + wv * 32 + xt * 16 + lrow) * CDIM;
#pragma unroll
        for (int ks = 0; ks < 4; ++ks) {
            const float4* s = reinterpret_cast<const float4*>(xr + ks * 32 + lhalf * 8);
            xfr[xt][ks] = cvt8v(s[0], s[1]);
        }
    }

    // row-major pass: Q (y==0) or K (y==1), swapped operands
    {
        const short* W    = isQ ? Wbf : Wbf + 16384;
        const float* bias = isQ ? bq : bk;
        const float  bsc  = isQ ? QSCALE : 1.0f;
        short* outp       = isQ ? Qp : Kp;

#pragma unroll
        for (int cf = 0; cf < 8; ++cf) {
            const short* wr = W + (cf * 16 + lrow) * CDIM;
            bf16x8 wfr[4];
#pragma unroll
            for (int ks = 0; ks < 4; ++ks)
                wfr[ks] = *reinterpret_cast<const bf16x8*>(wr + ks * 32 + lhalf * 8);
            float4 bv4 = *reinterpret_cast<const float4*>(bias + cf * 16 + lhalf * 4);
#pragma unroll
            for (int xt = 0; xt < 2; ++xt) {
                f32x4 acc = {0.f, 0.f, 0.f, 0.f};
#pragma unroll
                for (int ks = 0; ks < 4; ++ks)
                    acc = __builtin_amdgcn_mfma_f32_16x16x32_bf16(wfr[ks], xfr[xt][ks], acc, 0, 0, 0);
                union { bf16x4 v; unsigned u[2]; } pk;
                pk.u[0] = pk2(acc[0] + bv4.x * bsc, acc[1] + bv4.y * bsc);
                pk.u[1] = pk2(acc[2] + bv4.z * bsc, acc[3] + bv4.w * bsc);
                *reinterpret_cast<bf16x4*>(
                    outp + (size_t)(row0 + wv * 32 + xt * 16 + lrow) * CDIM
                         + cf * 16 + lhalf * 4) = pk.v;
            }
        }
    }

    // V pass (y==1): original operand order -> Vt[C][N] via LDS transpose
    if (!isQ) {
        const short* W = Wbf + 32768;
#pragma unroll
        for (int cf = 0; cf < 8; ++cf) {
            f32x4 acc0 = {0.f, 0.f, 0.f, 0.f};
            f32x4 acc1 = {0.f, 0.f, 0.f, 0.f};
            const short* wr = W + (cf * 16 + lrow) * CDIM;
#pragma unroll
            for (int ks = 0; ks < 4; ++ks) {
                bf16x8 bfr = *reinterpret_cast<const bf16x8*>(wr + ks * 32 + lhalf * 8);
                acc0 = __builtin_amdgcn_mfma_f32_16x16x32_bf16(xfr[0][ks], bfr, acc0, 0, 0, 0);
                acc1 = __builtin_amdgcn_mfma_f32_16x16x32_bf16(xfr[1][ks], bfr, acc1, 0, 0, 0);
            }
            const int col = cf * 16 + lrow;
            float bcol = bv[col];
            union { bf16x4 v; unsigned u[2]; } p0, p1;
            p0.u[0] = pk2(acc0[0] + bcol, acc0[1] + bcol);
            p0.u[1] = pk2(acc0[2] + bcol, acc0[3] + bcol);
            p1.u[0] = pk2(acc1[0] + bcol, acc1[1] + bcol);
            p1.u[1] = pk2(acc1[2] + bcol, acc1[3] + bcol);
            int base = col * 256 + wv * 64 + lhalf * 8;
            int sw   = (col & 7) << 4;
            *reinterpret_cast<bf16x4*>(vt_lds + ((base)      ^ sw)) = p0.v;
            *reinterpret_cast<bf16x4*>(vt_lds + ((base + 32) ^ sw)) = p1.v;
        }
        __syncthreads();
#pragma unroll
        for (int it = 0; it < 8; ++it) {
            int c   = it * 256 + tid;
            int col = c >> 4, rc = c & 15;
            int a   = (col * 256 + rc * 16) ^ ((col & 7) << 4);
            bf16x8 v = *reinterpret_cast<const bf16x8*>(vt_lds + a);
            *reinterpret_cast<bf16x8*>(Vt + (size_t)col * N + row0 + rc * 8) = v;
        }
    }
}

// ---------------------------------------------------------------------------
// Flash attention: double-buffered global_load_lds staging, counted vmcnt,
// raw s_barrier, swapped QK^T, packed P via cvt_pk, flat exp2 softmax.
// LDS: 2 x (K 16KB + Vt 16KB) + P 16KB = 80KB -> 2 blocks/CU.
// ---------------------------------------------------------------------------
__global__ __launch_bounds__(256) void attn_kernel(
    const short* __restrict__ Qp, const short* __restrict__ Kp,
    const short* __restrict__ VtG, const int* __restrict__ offset,
    float* __restrict__ out, int Ntot)
{
    __shared__ __align__(16) char smem[81920];
    char* lds_p = smem + 65536;

    // XCD-clustered mapping: all q-blocks of a segment on one XCD
    const int nq = LMAXC / QBLK;                 // 4
    int flat = blockIdx.x, total = gridDim.x;
    int seg, qb;
    if ((total & (8 * nq - 1)) == 0) {
        int per = total >> 3;                    // blocks per XCD
        int xcd = flat & 7;
        int wi  = flat >> 3;
        int sl  = wi / nq;
        qb  = wi - sl * nq;
        seg = xcd * (per / nq) + sl;
    } else { seg = flat / nq; qb = flat - seg * nq; }

    const int start = (seg == 0) ? 0 : offset[seg - 1];
    int len = offset[seg] - start;
    if (len > LMAXC) len = LMAXC;
    const int q0 = qb * QBLK;
    if (q0 >= len) return;

    const int tid   = threadIdx.x;
    const int lane  = tid & 63;
    const int wv    = tid >> 6;
    const int lrow  = lane & 15;
    const int lhalf = lane >> 4;
    const int ntiles = (len + KVBLK - 1) / KVBLK;
    const int lm1 = len - 1;

    // stage one K/Vt tile into buffer bb (8 gload_lds per wave)
    auto stage = [&](int kv0, int bb) {
        char* kb = smem + bb * 32768;
        char* vb = kb + 16384;
#pragma unroll
        for (int j = 0; j < 4; ++j) {
            int beta = j * 4096 + wv * 1024 + (lane << 4);
            // K: rows of 256B, inverse-swizzled source granule
            int r  = beta >> 8;
            int gs = ((beta >> 4) & 15) ^ (r & 7);
            int rg = kv0 + r; if (rg > lm1) rg = lm1;
            gload16(Kp + (((size_t)(start + rg)) << 7) + (gs << 3),
                    kb + j * 4096 + wv * 1024);
            // Vt: rows of 128B
            int d   = beta >> 7;
            int gs2 = ((beta >> 4) & 7) ^ (d & 7);
            long gk = (long)start + kv0 + (gs2 << 3);
            if (gk + 8 > Ntot) gk = Ntot - 8;
            gload16(VtG + (size_t)d * Ntot + gk,
                    vb + j * 4096 + wv * 1024);
        }
    };

    stage(0, 0);

    // Q fragments (2 q-tiles of 16 rows; wave owns 32 q rows)
    bf16x8 aq[2][4];
#pragma unroll
    for (int qt = 0; qt < 2; ++qt) {
        int qr = q0 + wv * 32 + qt * 16 + lrow;
        if (qr > lm1) qr = lm1;
        const short* qrow = Qp + (size_t)(start + qr) * CDIM;
#pragma unroll
        for (int ks = 0; ks < 4; ++ks)
            aq[qt][ks] = *reinterpret_cast<const bf16x8*>(qrow + ks * 32 + lhalf * 8);
    }

    f32x4 acc_o[2][8];
    float lsum[2] = {0.f, 0.f};
#pragma unroll
    for (int qt = 0; qt < 2; ++qt)
#pragma unroll
        for (int df = 0; df < 8; ++df) acc_o[qt][df] = (f32x4){0.f, 0.f, 0.f, 0.f};

    const int wbase = wv * 4096;

    for (int t = 0; t < ntiles; ++t) {
        const int kv0 = t * KVBLK;
        const int bb  = t & 1;
        if (t + 1 < ntiles) {
            stage(kv0 + KVBLK, bb ^ 1);
            asm volatile("s_waitcnt vmcnt(8)" ::: "memory");
        } else {
            asm volatile("s_waitcnt vmcnt(0)" ::: "memory");
        }
        blk_barrier();

        char* lds_k  = smem + bb * 32768;
        char* lds_vt = lds_k + 16384;
        const bool tail = (kv0 + KVBLK > len);

        // ---- S^T = K Q^T (swapped): lane holds q=lrow, keys kf*16+lhalf*4+r
        f32x4 s0[4], s1[4];
        __builtin_amdgcn_s_setprio(1);
#pragma unroll
        for (int kf = 0; kf < 4; ++kf) {
            s0[kf] = (f32x4){0.f, 0.f, 0.f, 0.f};
            s1[kf] = (f32x4){0.f, 0.f, 0.f, 0.f};
            int key = kf * 16 + lrow;
#pragma unroll
            for (int ks = 0; ks < 4; ++ks) {
                int kbo = (key * 256 + (ks * 32 + lhalf * 8) * 2) ^ ((key & 7) << 4);
                bf16x8 kfr = *reinterpret_cast<const bf16x8*>(lds_k + kbo);
                s0[kf] = __builtin_amdgcn_mfma_f32_16x16x32_bf16(kfr, aq[0][ks], s0[kf], 0, 0, 0);
                s1[kf] = __builtin_amdgcn_mfma_f32_16x16x32_bf16(kfr, aq[1][ks], s1[kf], 0, 0, 0);
            }
        }
        __builtin_amdgcn_s_setprio(0);

        // ---- flat softmax + packed P writes (keys contiguous per lane)
        const int keyb0 = kv0 + lhalf * 4;
#pragma unroll
        for (int qt = 0; qt < 2; ++qt) {
            const int qlocal = qt * 16 + lrow;
            const int rowoff = wbase + qlocal * 128;
            const int swz = pch(qlocal);
#pragma unroll
            for (int kf = 0; kf < 4; ++kf) {
                f32x4 sv = qt ? s1[kf] : s0[kf];
                float p[4];
#pragma unroll
                for (int r = 0; r < 4; ++r) {
                    float pv = exp2f(sv[r]);
                    if (tail && (keyb0 + kf * 16 + r >= len)) pv = 0.f;
                    p[r] = pv;
                    lsum[qt] += pv;
                }
                unsigned long long w =
                    (unsigned long long)pk2(p[0], p[1]) |
                    ((unsigned long long)pk2(p[2], p[3]) << 32);
                *reinterpret_cast<unsigned long long*>(
                    lds_p + rowoff + ((kf * 32 + lhalf * 8) ^ swz)) = w;
            }
        }

        // ---- O += P V  (per-wave P region, no barrier needed)
        __builtin_amdgcn_s_setprio(1);
#pragma unroll
        for (int ks2 = 0; ks2 < 2; ++ks2) {
            bf16x8 ap0 = *reinterpret_cast<const bf16x8*>(
                lds_p + wbase + lrow * 128 + ((ks2 * 64 + lhalf * 16) ^ pch(lrow)));
            bf16x8 ap1 = *reinterpret_cast<const bf16x8*>(
                lds_p + wbase + (16 + lrow) * 128 + ((ks2 * 64 + lhalf * 16) ^ pch(16 + lrow)));
            int k0 = ks2 * 32 + lhalf * 8;
#pragma unroll
            for (int df = 0; df < 8; ++df) {
                int d = df * 16 + lrow;
                int vb2 = (d * 128 + k0 * 2) ^ ((d & 7) << 4);
                bf16x8 bvf = *reinterpret_cast<const bf16x8*>(lds_vt + vb2);
                acc_o[0][df] = __builtin_amdgcn_mfma_f32_16x16x32_bf16(ap0, bvf, acc_o[0][df], 0, 0, 0);
                acc_o[1][df] = __builtin_amdgcn_mfma_f32_16x16x32_bf16(ap1, bvf, acc_o[1][df], 0, 0, 0);
            }
        }
        __builtin_amdgcn_s_setprio(0);

        blk_barrier();
    }

    // ---- epilogue: reduce l across the 4-lane group, redistribute, store
#pragma unroll
    for (int qt = 0; qt < 2; ++qt) {
        float l = lsum[qt];
        l += __shfl_xor(l, 16);
        l += __shfl_xor(l, 32);          // lane now has full sum for q=lrow
        float rinv[4];
#pragma unroll
        for (int r = 0; r < 4; ++r)
            rinv[r] = 1.0f / __shfl(l, lhalf * 4 + r);
#pragma unroll
        for (int df = 0; df < 8; ++df)
#pragma unroll
            for (int r = 0; r < 4; ++r) {
                int qg = q0 + wv * 32 + qt * 16 + lhalf * 4 + r;
                if (qg < len)
                    out[(size_t)(start + qg) * CDIM + df * 16 + lrow]
                        = acc_o[qt][df][r] * rinv[r];
            }
    }
}

extern "C" void kernel_launch(void* const* d_in, const int* in_sizes, int n_in,
                              void* d_out, int out_size, void* d_ws, size_t ws_size,
                              hipStream_t stream) {
    const float* Qf = (const float*)d_in[0];
    const float* Kf = (const float*)d_in[1];
    const float* Wq = (const float*)d_in[2];
    const float* bq = (const float*)d_in[3];
    const float* Wk = (const float*)d_in[4];
    const float* bk = (const float*)d_in[5];
    const float* Wv = (const float*)d_in[6];
    const float* bv_ = (const float*)d_in[7];
    const int* offset = (const int*)d_in[8];

    const int N = in_sizes[0] / CDIM;     // 262144
    const int B = in_sizes[8];            // 512

    short* Qp = (short*)d_ws;
    short* Kp = Qp + (size_t)N * CDIM;
    short* Vt = Kp + (size_t)N * CDIM;    // [C][N]
    float* out = (float*)d_out;

    size_t base_need = (size_t)3 * N * CDIM * 2;
    short* Wbf = (ws_size >= base_need + 3 * 16384 * 2)
               ? (Vt + (size_t)N * CDIM) : (short*)d_out;

    wcvt_kernel<<<24, 256, 0, stream>>>(Wq, Wk, Wv, Wbf);

    dim3 pgrid(N / 128, 2);
    proj_kernel<<<pgrid, 256, 0, stream>>>(Qf, Kf, Wbf, bq, bk, bv_,
                                           Qp, Kp, Vt, N);

    attn_kernel<<<dim3(B * (LMAXC / QBLK)), 256, 0, stream>>>(
        Qp, Kp, Vt, offset, out, N);
}